// Round 16
// baseline (138.120 us; speedup 1.0000x reference)
//
#include <hip/hip_runtime.h>

namespace {

constexpr int Bn = 2;
constexpr int Dn = 64;
constexpr int Hn = 96;
constexpr int Wn = 96;
constexpr int HW = Hn * Wn;          // 9216
constexpr int S  = Dn * HW;          // 589824 per (vol,batch) slab
constexpr int NBS = Bn * S;          // 1179648
constexpr int NT  = 2 * NBS;         // 2359296 (slabs: predB0,predB1,truthB0,truthB1)
constexpr int WPP = HW / 32;         // 288 words per z-plane
constexpr int WPS = S / 32;          // 18432 words per slab
constexpr int NTW = NT / 32;         // 73728 packed words
constexpr float EPSf = 1e-7f;
constexpr int BLK_SUMS = NBS / 4 / 256;   // 1152
#define BIGF 1e12f                   // RN(1e12): exact all-foreground EDT value
constexpr int LINF = 1 << 20;

// ---- K1: binarize + z-L1 distance (u8, 255=inf) via bit-scan (R15-verified) ----
__global__ __launch_bounds__(256) void k_bin0(const float* __restrict__ logits,
                                              const int* __restrict__ labels,
                                              unsigned char* __restrict__ DZ) {
  __shared__ unsigned bits[64];
  __shared__ unsigned zlo[32], zhi[32];
  int slab = blockIdx.x / 288;                 // 1152 blocks = 4 slabs x 288 groups
  int cg = blockIdx.x - slab * 288;
  int c0 = cg * 32;
  int tid = threadIdx.x;
  int lane = tid & 63;
  for (int t = tid; t < 2048; t += 256) {
    int zz = t >> 5;
    int col = t & 31;
    int s = zz * HW + c0 + col;
    bool v;
    if (slab < 2) {
      float l0 = logits[(slab * 2 + 0) * S + s];
      float l1 = logits[(slab * 2 + 1) * S + s];
      v = l1 > l0;                             // softmax(p1)>0.5 <=> l1>l0
    } else {
      v = labels[(slab - 2) * S + s] > 0;
    }
    unsigned long long m = __ballot(v);
    if (lane == 0)       bits[zz] = (unsigned)m;
    else if (lane == 32) bits[zz] = (unsigned)(m >> 32);
  }
  __syncthreads();
  if (tid < 64) {
    int col = tid & 31;
    int base = (tid < 32) ? 0 : 32;
    unsigned zw = 0u;
    #pragma unroll
    for (int j = 0; j < 32; ++j)
      zw |= (((bits[base + j] >> col) & 1u) ^ 1u) << j;
    if (tid < 32) zlo[col] = zw; else zhi[col] = zw;
  }
  __syncthreads();
  int col = tid & 31;
  int chunk = tid >> 5;
  int i0 = chunk * 8;
  unsigned long long Z = ((unsigned long long)zhi[col] << 32) | (unsigned long long)zlo[col];
  unsigned char* o1 = DZ + slab * S + c0 + col;
  #pragma unroll
  for (int s = 0; s < 8; ++s) {
    int i = i0 + s;
    unsigned long long below = Z & ((2ull << i) - 1ull);
    unsigned long long above = Z >> i;
    unsigned char dv;
    if (below | above) {
      int ddn = below ? (i - (63 - __builtin_clzll(below))) : 99;
      int dup = above ? __builtin_ctzll(above) : 99;
      int d = ddn < dup ? ddn : dup;           // <= 63
      dv = (unsigned char)d;
    } else {
      dv = 255;
    }
    o1[i * HW] = dv;
  }
}

// ---- K2: windowed EDT (y,x) + 3-plane L1 + skel + pmax, quarter-plane/block ----
// All math R14/R15-verified: window bound Euclid<=L1 (exact ints), cap-12 skel
// compare, 255=inf sentinels, OOB planes/rows -> 0 (max-neutral).
__global__ __launch_bounds__(256) void k_edtskel(const unsigned char* __restrict__ DZ,
                                                 float* __restrict__ EF,
                                                 unsigned* __restrict__ SKELB,
                                                 float* __restrict__ pmax) {
  __shared__ __align__(16) unsigned char shm[49760];
  unsigned char* dzl = shm;                    // 3 x 9216 (planes z-1,z,z+1)
  unsigned char* t1l = shm + 27648;            // 3 x 26 x 96 (zy-L1, 255=inf)
  unsigned char* d1l = shm + 35136;            // 3 x 26 x 96 (3D L1, 255=inf)
  unsigned short* o1 = (unsigned short*)(shm + 42624);  // 24 x 96 (pass1, 0xFFFF=inf)
  unsigned char* zm  = shm + 47232;            // 26 x 96 (z-max of min(d1,12))
  float* ldsf = (float*)(shm + 49744);
  int slab = blockIdx.x >> 8;                  // 1024 = slab(4) x z(64) x q(4)
  int z = (blockIdx.x >> 2) & 63;
  int y0 = (blockIdx.x & 3) * 24;
  int tid = threadIdx.x;
  int pb = slab * S + z * HW;
  // stage dz for planes z-1,z,z+1 (OOB -> 255)
  for (int t = tid; t < 1728; t += 256) {
    int p = t / 576;
    int idx = t - p * 576;
    int zp = z - 1 + p;
    uint4 val;
    if (zp >= 0 && zp < Dn)
      val = ((const uint4*)(DZ + slab * S + zp * HW))[idx];
    else
      val = make_uint4(0xFFFFFFFFu, 0xFFFFFFFFu, 0xFFFFFFFFu, 0xFFFFFFFFu);
    ((uint4*)dzl)[t] = val;
  }
  __syncthreads();
  // t1 scans: 3 planes x 96 cols; rows yy = y0-1 .. y0+24 (26)
  for (int task = tid; task < 288; task += 256) {
    int p = task / 96;
    int xx = task - p * 96;
    int zp = z - 1 + p;
    if (zp < 0 || zp >= Dn) continue;          // t1 of OOB plane unused
    const unsigned char* dzp = dzl + p * HW;
    int P = LINF;
    int A[26];
    for (int j = 0; j < y0 - 1; ++j) {
      int v = dzp[j * 96 + xx]; if (v == 255) v = LINF;
      P = min(P, v - j);
    }
    #pragma unroll
    for (int s = 0; s < 26; ++s) {
      int j = y0 - 1 + s;
      if (j >= 0 && j < 96) {
        int v = dzp[j * 96 + xx]; if (v == 255) v = LINF;
        P = min(P, v - j);
        A[s] = j + P;
      } else A[s] = LINF;
    }
    int Sv = LINF;
    for (int j = 95; j >= y0 + 25; --j) {
      int v = dzp[j * 96 + xx]; if (v == 255) v = LINF;
      Sv = min(Sv, v + j);
    }
    #pragma unroll
    for (int s = 25; s >= 0; --s) {
      int j = y0 - 1 + s;
      int t = 255;
      if (j >= 0 && j < 96) {
        int v = dzp[j * 96 + xx]; if (v == 255) v = LINF;
        Sv = min(Sv, v + j);
        int tv = min(A[s], Sv - j);            // finite <= 158
        t = tv > 254 ? 255 : tv;
      }
      t1l[p * 2496 + s * 96 + xx] = (unsigned char)t;
    }
  }
  __syncthreads();
  // pass1 windowed (center plane): o1[rr][xx], window r = t1, cand f = dz^2
  for (int v = tid; v < 2304; v += 256) {
    int rr = v / 96;
    int xx = v - rr * 96;
    int y = y0 + rr;
    int r = t1l[1 * 2496 + (rr + 1) * 96 + xx];
    unsigned short res;
    if (r == 255) {
      res = 0xFFFFu;
    } else {
      int lo = y - r; if (lo < 0) lo = 0;
      int hi = y + r; if (hi > 95) hi = 95;
      int best = 1 << 30;
      const unsigned char* dzc = dzl + 1 * HW + xx;
      for (int j = lo; j <= hi; ++j) {
        int dv = dzc[j * 96];
        if (dv != 255) {
          int dd = y - j;
          best = min(best, dd * dd + dv * dv);
        }
      }
      res = (unsigned short)best;              // <= t1^2 <= 24964
    }
    o1[rr * 96 + xx] = res;
  }
  // d1 row scans: 3 planes x 26 rows (fwd into d1l, then bwd combine in place)
  for (int task = tid; task < 78; task += 256) {
    int p = task / 26;
    int rr = task - p * 26;
    int zp = z - 1 + p;
    int yy = y0 - 1 + rr;
    unsigned char* drow = d1l + p * 2496 + rr * 96;
    if (zp < 0 || zp >= Dn || yy < 0 || yy >= Hn) {
      for (int j = 0; j < 96; ++j) drow[j] = 0; // OOB -> 0 (max-neutral)
      continue;
    }
    const unsigned char* trow = t1l + p * 2496 + rr * 96;
    int P = LINF;
    for (int j = 0; j < 96; ++j) {
      int v = trow[j]; if (v == 255) v = LINF;
      P = min(P, v - j);
      int a = j + P;
      drow[j] = (unsigned char)(a > 254 ? 255 : a);
    }
    int Sv = LINF;
    for (int j = 95; j >= 0; --j) {
      int v = trow[j]; if (v == 255) v = LINF;
      Sv = min(Sv, v + j);
      int b = Sv - j;
      int f = drow[j];
      int d = min(f, b > 254 ? 255 : b);       // finite <= 253, 255 = inf
      drow[j] = (unsigned char)d;
    }
  }
  __syncthreads();
  // zm[rr][x] = max over 3 planes of min(d1,12)
  for (int t = tid; t < 2496; t += 256) {
    int a0 = min((int)d1l[t], 12);
    int a1 = min((int)d1l[2496 + t], 12);
    int a2 = min((int)d1l[4992 + t], 12);
    int m = a0 > a1 ? a0 : a1;
    zm[t] = (unsigned char)(m > a2 ? m : a2);
  }
  __syncthreads();
  // fused pass2 + skel + ballot + pmax
  float mm = 0.0f;
  int wbase = slab * WPS + z * WPP + y0 * 3;
  int lane = tid & 63;
  #pragma unroll
  for (int round = 0; round < 9; ++round) {
    int v = round * 256 + tid;
    int rr = v / 96;                           // tile row 0..23 (d1l/zm row rr+1)
    int x = v - rr * 96;
    int d1v = d1l[1 * 2496 + (rr + 1) * 96 + x];
    float outf;
    if (d1v == 255) {
      outf = BIGF;
    } else {
      int lo = x - d1v; if (lo < 0) lo = 0;
      int hi = x + d1v; if (hi > 95) hi = 95;
      int best = 1 << 30;
      const unsigned short* orow = o1 + rr * 96;
      for (int j = lo; j <= hi; ++j) {
        unsigned short f = orow[j];
        if (f != 0xFFFFu) {
          int dd = x - j;
          best = min(best, dd * dd + (int)f);
        }
      }
      outf = (float)best;                      // <= 64009, exact in f32
    }
    // skel: d1c == max3x3x3(min(d1,12)) and 1<=d1c<=11
    int b1 = (rr + 1) * 96 + x;
    unsigned char mx = zm[b1 - 96];
    { unsigned char a = zm[b1]; mx = mx > a ? mx : a; }
    { unsigned char a = zm[b1 + 96]; mx = mx > a ? mx : a; }
    if (x > 0) {
      unsigned char a0 = zm[b1 - 97], a1 = zm[b1 - 1], a2 = zm[b1 + 95];
      unsigned char a = a0 > a1 ? a0 : a1; a = a > a2 ? a : a2;
      mx = mx > a ? mx : a;
    }
    if (x < Wn - 1) {
      unsigned char a0 = zm[b1 - 95], a1 = zm[b1 + 1], a2 = zm[b1 + 97];
      unsigned char a = a0 > a1 ? a0 : a1; a = a > a2 ? a : a2;
      mx = mx > a ? mx : a;
    }
    int d1c = min(d1v, 12);
    bool sk = (d1c == (int)mx) && (d1c >= 1) && (d1c <= 11);
    unsigned long long bal = __ballot(sk);
    if (lane == 0)       SKELB[wbase + (v >> 5)] = (unsigned)bal;
    else if (lane == 32) SKELB[wbase + (v >> 5)] = (unsigned)(bal >> 32);
    if (sk) mm = fmaxf(mm, outf);
    EF[pb + (y0 + rr) * 96 + x] = outf;
  }
  #pragma unroll
  for (int o = 32; o > 0; o >>= 1) mm = fmaxf(mm, __shfl_xor(mm, o, 64));
  if (lane == 0) ldsf[tid >> 6] = mm;
  __syncthreads();
  if (tid == 0)
    pmax[blockIdx.x] = fmaxf(fmaxf(ldsf[0], ldsf[1]), fmaxf(ldsf[2], ldsf[3]));
}

// ---- K3: sums (R12-verified; plain partial stores) ----
__global__ __launch_bounds__(256) void k_sums(const float* __restrict__ d2,
                                              const unsigned* __restrict__ skel,
                                              const float* __restrict__ pmax,
                                              double* __restrict__ ps) {
  __shared__ float lmax[4];
  __shared__ double ldsd[4][4];
  int tid = threadIdx.x;
  {
    int wave = tid >> 6, lane = tid & 63;
    const float* pw = pmax + wave * 256;
    float v = fmaxf(fmaxf(pw[lane], pw[lane + 64]),
                    fmaxf(pw[lane + 128], pw[lane + 192]));
    #pragma unroll
    for (int o = 32; o > 0; o >>= 1) v = fmaxf(v, __shfl_xor(v, o, 64));
    if (lane == 0) lmax[wave] = v;
  }
  __syncthreads();
  int q = blockIdx.x * 256 + tid;
  int idx0 = q * 4;
  int b = idx0 / S;
  float rmax_p = sqrtf(lmax[b]);
  float rmax_t = sqrtf(lmax[2 + b]);
  float4 dp4 = ((const float4*)d2)[q];
  float4 dt4 = ((const float4*)(d2 + NBS))[q];
  unsigned spw = (skel[idx0 >> 5] >> (idx0 & 31)) & 0xFu;
  unsigned stw = (skel[(NBS + idx0) >> 5] >> (idx0 & 31)) & 0xFu;
  const float* dp = &dp4.x;
  const float* dt = &dt4.x;
  double acc[4] = {0.0, 0.0, 0.0, 0.0};
  #pragma unroll
  for (int s = 0; s < 4; ++s) {
    float dist_p = sqrtf(dp[s]);
    float dist_t = sqrtf(dt[s]);
    bool sp = (spw >> s) & 1u;
    bool st = (stw >> s) & 1u;
    float q_vp = (rmax_p > 0.0f) ? dist_p / rmax_p : dist_p;
    float q_vl = (rmax_t > 0.0f) ? dist_t / rmax_t : dist_t;
    float q_spvp = sp ? q_vp : 0.0f;
    float q_slvl = st ? q_vl : 0.0f;
    float q_sp = sp ? (1.0f + EPSf) / (q_spvp * q_spvp + EPSf) : 0.0f;
    float q_sl = st ? (1.0f + EPSf) / (q_slvl * q_slvl + EPSf) : 0.0f;
    acc[0] += (double)(q_sp * q_vl);
    acc[1] += (double)(((q_spvp != 0.0f) && (q_slvl == 0.0f)) ? q_spvp * q_sp
                                                              : q_slvl * q_sp);
    acc[2] += (double)(q_sl * q_vp);
    acc[3] += (double)(((q_slvl != 0.0f) && (q_spvp == 0.0f)) ? q_slvl * q_sl
                                                              : q_spvp * q_sl);
  }
  #pragma unroll
  for (int k = 0; k < 4; ++k)
    #pragma unroll
    for (int o = 32; o > 0; o >>= 1)
      acc[k] += __shfl_xor(acc[k], o, 64);
  if ((tid & 63) == 0) {
    #pragma unroll
    for (int k = 0; k < 4; ++k) ldsd[tid >> 6][k] = acc[k];
  }
  __syncthreads();
  if (tid == 0) {
    #pragma unroll
    for (int k = 0; k < 4; ++k)
      ps[blockIdx.x * 4 + k] = ldsd[0][k] + ldsd[1][k] + ldsd[2][k] + ldsd[3][k];
  }
}

// ---- K4: final reduce + loss ----
__global__ __launch_bounds__(256) void k_final(const double* __restrict__ ps,
                                               float* __restrict__ out) {
  __shared__ double ldsd[4][4];
  int tid = threadIdx.x;
  double s[4] = {0.0, 0.0, 0.0, 0.0};
  for (int i = tid; i < BLK_SUMS; i += 256) {
    s[0] += ps[i * 4 + 0];
    s[1] += ps[i * 4 + 1];
    s[2] += ps[i * 4 + 2];
    s[3] += ps[i * 4 + 3];
  }
  #pragma unroll
  for (int k = 0; k < 4; ++k)
    #pragma unroll
    for (int o = 32; o > 0; o >>= 1)
      s[k] += __shfl_xor(s[k], o, 64);
  if ((tid & 63) == 0) {
    #pragma unroll
    for (int k = 0; k < 4; ++k) ldsd[tid >> 6][k] = s[k];
  }
  __syncthreads();
  if (tid == 0) {
    double tot[4];
    #pragma unroll
    for (int k = 0; k < 4; ++k)
      tot[k] = ldsd[0][k] + ldsd[1][k] + ldsd[2][k] + ldsd[3][k];
    double wp = (tot[0] + 1.0) / (tot[1] + 1.0);
    double ws = (tot[2] + 1.0) / (tot[3] + 1.0);
    out[0] = (float)(1.0 - 2.0 * (wp * ws) / (wp + ws));
  }
}

} // namespace

extern "C" void kernel_launch(void* const* d_in, const int* in_sizes, int n_in,
                              void* d_out, int out_size, void* d_ws, size_t ws_size,
                              hipStream_t stream) {
  (void)in_sizes; (void)n_in; (void)out_size; (void)ws_size;
  const float* logits = (const float*)d_in[0];   // [B,2,D,H,W] f32
  const int* labels   = (const int*)d_in[1];     // [B,1,D,H,W] i32
  float* out = (float*)d_out;

  float* EF = (float*)d_ws;                        // final Euclidean d2 (f32)
  unsigned char* DZ  = (unsigned char*)(EF + NT);  // z-L1 (u8, 255=inf)
  unsigned* SKELB = (unsigned*)(DZ + NT);
  float* PMAX  = (float*)(SKELB + NTW);            // 1024 per-tile masked maxes
  double* PS   = (double*)(PMAX + 1024);           // 1152x4 doubles (8B-aligned)

  k_bin0<<<1152, 256, 0, stream>>>(logits, labels, DZ);
  k_edtskel<<<1024, 256, 0, stream>>>(DZ, EF, SKELB, PMAX);
  k_sums<<<1152, 256, 0, stream>>>(EF, SKELB, PMAX, PS);
  k_final<<<1, 256, 0, stream>>>(PS, out);
}